// Round 4
// baseline (399.298 us; speedup 1.0000x reference)
//
#include <hip/hip_runtime.h>
#include <hip/hip_bf16.h>
#include <cstdint>
#include <type_traits>

// Problem constants (reference: N=8192, D=2048, M=512, E=4, SCALE=1)
#define N_TOK 8192
#define DDIM  2048
#define MDIM  512
#define NEXP  4

typedef __bf16 bf16x4 __attribute__((ext_vector_type(4)));
typedef __bf16 bf16x8 __attribute__((ext_vector_type(8)));
typedef float  f32x4  __attribute__((ext_vector_type(4)));

// ---------------------------------------------------------------------------
// Scratch in module device globals (fully rewritten every call).
// ---------------------------------------------------------------------------
__device__ int g_counts[NEXP];
__device__ int g_idx[NEXP * N_TOK];
__device__ __hip_bfloat16 g_H[(size_t)N_TOK * MDIM];   // 8 MB hidden acts (bf16)

__global__ void zero_counts_kernel() {
    if (threadIdx.x < NEXP) g_counts[threadIdx.x] = 0;
}

// ---------------------------------------------------------------------------
// Bucket tokens by expert; auto-detect int32 vs int64 domains on device.
// ---------------------------------------------------------------------------
__global__ void bucket_kernel(const void* __restrict__ domv) {
    __shared__ int mode64;
    if (threadIdx.x == 0) {
        const long long* d64 = (const long long*)domv;
        int m = 1;
        for (int i = 0; i < 64; ++i) {
            long long v = d64[i];
            if (v < 0 || v >= NEXP) { m = 0; break; }
        }
        mode64 = m;
    }
    __syncthreads();
    const int i = blockIdx.x * blockDim.x + threadIdx.x;
    if (i < N_TOK) {
        int e = mode64 ? (int)((const long long*)domv)[i]
                       : ((const int*)domv)[i];
        int slot = atomicAdd(&g_counts[e], 1);
        g_idx[e * N_TOK + slot] = i;
    }
}

__device__ __forceinline__ bf16x4 cvt4(f32x4 v) {
    bf16x4 r;
    r[0] = (__bf16)v[0]; r[1] = (__bf16)v[1];
    r[2] = (__bf16)v[2]; r[3] = (__bf16)v[3];
    return r;
}

// ---------------------------------------------------------------------------
// Grouped NT GEMM over expert-gathered rows, fp32 inputs, bf16 MFMA compute.
//   C[t,col] = act( sum_k A[t,k]*B[e,col,k] + bias[e,col] ) (+ resid[t,col])
// Tile 128x128x32; 256 threads = 4 waves (2x2), each 64x64 via 16x16x32 MFMA.
// TA: dtype of A (float for x, bf16 for H). B/bias/resid are fp32. TC: out.
// ---------------------------------------------------------------------------
template <typename TA, typename TC, int KDIM, int NCOLS, bool RELU, bool RESID>
__device__ __forceinline__ void gemm_core(const TA* __restrict__ A,
                                          const float* __restrict__ B,
                                          const float* __restrict__ bias,
                                          const float* __restrict__ resid,
                                          TC* __restrict__ C) {
    const int e   = blockIdx.z;
    const int rt  = blockIdx.y;            // row (token-slot) tile
    const int ct  = blockIdx.x;            // col tile
    const int cnt = g_counts[e];
    if (rt * 128 >= cnt) return;           // uniform across block

    __shared__ __align__(16) __hip_bfloat16 sA[128 * 32];
    __shared__ __align__(16) __hip_bfloat16 sB[128 * 32];
    __shared__ int sTok[128];

    const int tid = threadIdx.x;

    if (tid < 128) {
        int slot = rt * 128 + tid;
        int cs   = slot < cnt ? slot : cnt - 1;   // clamp partial tile (dup row)
        sTok[tid] = g_idx[e * N_TOK + cs];
    }
    __syncthreads();

    // --- B staging ptrs (fp32, 4 chunks of float4 per thread) ---
    // chunk c = tid + 256p: row = (tid>>3)+32p, col = (tid&7)*4
    const size_t bbase = ((size_t)e * NCOLS + (size_t)ct * 128) * KDIM;
    const int bcol = (tid & 7) * 4;
    const float* gB[4];
#pragma unroll
    for (int p = 0; p < 4; ++p)
        gB[p] = B + bbase + (size_t)((tid >> 3) + 32 * p) * KDIM + bcol;

    // --- A staging ptrs ---
    const TA* gAf[4];                       // fp32 path
    const TA* gAh0 = nullptr, *gAh1 = nullptr;  // bf16 path
    if constexpr (std::is_same<TA, float>::value) {
#pragma unroll
        for (int p = 0; p < 4; ++p)
            gAf[p] = A + (size_t)sTok[(tid >> 3) + 32 * p] * KDIM + bcol;
    } else {
        gAh0 = A + (size_t)sTok[tid >> 2] * KDIM + (tid & 3) * 8;
        gAh1 = A + (size_t)sTok[(tid >> 2) + 64] * KDIM + (tid & 3) * 8;
    }

    const int wave = tid >> 6;
    const int lane = tid & 63;
    const int wm = (wave >> 1) * 64;       // wave row offset in tile
    const int wn = (wave & 1) * 64;        // wave col offset in tile
    const int frow = lane & 15;
    const int fk   = (lane >> 4) * 8;

    f32x4 acc[4][4] = {};

    for (int k0 = 0; k0 < KDIM; k0 += 32) {
        // global -> registers
        f32x4 rb[4];
#pragma unroll
        for (int p = 0; p < 4; ++p) rb[p] = *(const f32x4*)(gB[p] + k0);

        f32x4 raf[4];
        bf16x8 rah0, rah1;
        if constexpr (std::is_same<TA, float>::value) {
#pragma unroll
            for (int p = 0; p < 4; ++p) raf[p] = *(const f32x4*)(gAf[p] + k0);
        } else {
            rah0 = *(const bf16x8*)(gAh0 + k0);
            rah1 = *(const bf16x8*)(gAh1 + k0);
        }

        __syncthreads();   // prev iteration's LDS consumers done

        // registers -> LDS (cvt fp32 -> bf16)
#pragma unroll
        for (int p = 0; p < 4; ++p)
            *(bf16x4*)&sB[((tid >> 3) + 32 * p) * 32 + bcol] = cvt4(rb[p]);
        if constexpr (std::is_same<TA, float>::value) {
#pragma unroll
            for (int p = 0; p < 4; ++p)
                *(bf16x4*)&sA[((tid >> 3) + 32 * p) * 32 + bcol] = cvt4(raf[p]);
        } else {
            *(bf16x8*)&sA[tid * 8]         = rah0;
            *(bf16x8*)&sA[(tid + 256) * 8] = rah1;
        }
        __syncthreads();   // staged data visible to all waves

        bf16x8 af[4], bfr[4];
        const __hip_bfloat16* aptr = &sA[(wm + frow) * 32 + fk];
        const __hip_bfloat16* bptr = &sB[(wn + frow) * 32 + fk];
#pragma unroll
        for (int i = 0; i < 4; ++i) af[i]  = *(const bf16x8*)(aptr + i * 16 * 32);
#pragma unroll
        for (int j = 0; j < 4; ++j) bfr[j] = *(const bf16x8*)(bptr + j * 16 * 32);
#pragma unroll
        for (int i = 0; i < 4; ++i)
#pragma unroll
            for (int j = 0; j < 4; ++j)
                acc[i][j] = __builtin_amdgcn_mfma_f32_16x16x32_bf16(
                    af[i], bfr[j], acc[i][j], 0, 0, 0);
    }

    // epilogue: C/D layout col=lane&15, row=(lane>>4)*4+r  [m89/m91]
    const int crow = (lane >> 4) * 4;
    const int ccol = lane & 15;
#pragma unroll
    for (int j = 0; j < 4; ++j) {
        const int col = ct * 128 + wn + j * 16 + ccol;
        const float bv = bias[(size_t)e * NCOLS + col];
#pragma unroll
        for (int i = 0; i < 4; ++i) {
            const int rl = wm + i * 16 + crow;
#pragma unroll
            for (int r = 0; r < 4; ++r) {
                const int slot = rt * 128 + rl + r;
                if (slot < cnt) {
                    const int t = sTok[rl + r];
                    float v = acc[i][j][r] + bv;
                    if (RELU)  v = fmaxf(v, 0.0f);
                    if (RESID) v += resid[(size_t)t * NCOLS + col];
                    if constexpr (std::is_same<TC, float>::value)
                        C[(size_t)t * NCOLS + col] = v;
                    else
                        C[(size_t)t * NCOLS + col] = __float2bfloat16(v);
                }
            }
        }
    }
}

__global__ __launch_bounds__(256)
void gemm1_kernel(const float* __restrict__ x,
                  const float* __restrict__ W1,
                  const float* __restrict__ b1) {
    gemm_core<float, __hip_bfloat16, DDIM, MDIM, true, false>(x, W1, b1, nullptr, g_H);
}

__global__ __launch_bounds__(256)
void gemm2_kernel(const float* __restrict__ x,
                  const float* __restrict__ W2,
                  const float* __restrict__ b2,
                  float* __restrict__ out) {
    gemm_core<__hip_bfloat16, float, MDIM, DDIM, false, true>(
        (const __hip_bfloat16*)g_H, W2, b2, x, out);
}

extern "C" void kernel_launch(void* const* d_in, const int* in_sizes, int n_in,
                              void* d_out, int out_size, void* d_ws, size_t ws_size,
                              hipStream_t stream) {
    const float* x  = (const float*)d_in[0];
    const void*  dm = d_in[1];
    const float* W1 = (const float*)d_in[2];
    const float* b1 = (const float*)d_in[3];
    const float* W2 = (const float*)d_in[4];
    const float* b2 = (const float*)d_in[5];
    float* out = (float*)d_out;

    zero_counts_kernel<<<1, 64, 0, stream>>>();
    bucket_kernel<<<N_TOK / 256, 256, 0, stream>>>(dm);

    // GEMM1: H = relu(x @ W1[e]^T + b1[e])   [K=2048, cols=512]
    gemm1_kernel<<<dim3(MDIM / 128, N_TOK / 128, NEXP), 256, 0, stream>>>(x, W1, b1);

    // GEMM2: out = x + H @ W2[e]^T + b2[e]   [K=512, cols=2048]
    gemm2_kernel<<<dim3(DDIM / 128, N_TOK / 128, NEXP), 256, 0, stream>>>(x, W2, b2, out);
}

// Round 5
// 315.207 us; speedup vs baseline: 1.2668x; 1.2668x over previous
//
#include <hip/hip_runtime.h>
#include <hip/hip_bf16.h>
#include <cstdint>
#include <type_traits>

// Problem constants (reference: N=8192, D=2048, M=512, E=4, SCALE=1)
#define N_TOK 8192
#define DDIM  2048
#define MDIM  512
#define NEXP  4

typedef __bf16 bf16x4 __attribute__((ext_vector_type(4)));
typedef __bf16 bf16x8 __attribute__((ext_vector_type(8)));
typedef float  f32x4  __attribute__((ext_vector_type(4)));

// ---------------------------------------------------------------------------
// Scratch in module device globals (fully rewritten every call).
// ---------------------------------------------------------------------------
__device__ int g_counts[NEXP];
__device__ int g_idx[NEXP * N_TOK];
__device__ __hip_bfloat16 g_H[(size_t)N_TOK * MDIM];   // 8 MB hidden acts (bf16)

__global__ void zero_counts_kernel() {
    if (threadIdx.x < NEXP) g_counts[threadIdx.x] = 0;
}

// ---------------------------------------------------------------------------
// Bucket tokens by expert — wave-aggregated atomics (4 atomicAdds per wave
// instead of 64; round-4's 8192 atomics on 4 addresses was ~100 us of
// serialized contention). Domains dtype (int32 vs int64) detected by ballot.
// ---------------------------------------------------------------------------
__global__ void bucket_kernel(const void* __restrict__ domv) {
    const int i    = blockIdx.x * blockDim.x + threadIdx.x;
    const int lane = threadIdx.x & 63;

    // dtype detect: if the first 64 int64-views are all in [0,NEXP), it's int64
    const long long* d64 = (const long long*)domv;
    long long probe = d64[lane];
    bool mode64 = (__ballot(probe >= 0 && probe < NEXP) == ~0ull);

    const int e = mode64 ? (int)d64[i] : ((const int*)domv)[i];

#pragma unroll
    for (int ex = 0; ex < NEXP; ++ex) {
        unsigned long long m = __ballot(e == ex);
        if (m == 0) continue;                    // wave-uniform branch
        int cnt    = __popcll(m);
        int leader = __ffsll((long long)m) - 1;
        int base   = 0;
        if (lane == leader) base = atomicAdd(&g_counts[ex], cnt);
        base = __shfl(base, leader);
        if (e == ex) {
            int prefix = __popcll(m & ((1ull << lane) - 1ull));
            g_idx[ex * N_TOK + base + prefix] = i;
        }
    }
}

__device__ __forceinline__ bf16x4 cvt4(f32x4 v) {
    bf16x4 r;
    r[0] = (__bf16)v[0]; r[1] = (__bf16)v[1];
    r[2] = (__bf16)v[2]; r[3] = (__bf16)v[3];
    return r;
}

// ---------------------------------------------------------------------------
// Grouped NT GEMM over expert-gathered rows, bf16 MFMA compute.
//   C[t,col] = act( sum_k A[t,k]*B[e,col,k] + bias[e,col] ) (+ resid[t,col])
// Tile 64x64x32; 256 threads = 4 waves (2x2), each wave 32x32 via 2x2 of
// 16x16x32 MFMA. rt = blockIdx.x (fast dim) so the ct-blocks sharing the same
// gathered A rows are 128 apart in linear block id -> same XCD (id%8) -> A-row
// reuse served by that XCD's L2.
// Register-prefetch rotation: next K-tile's global loads issue right after the
// second barrier, overlapping ds_read+MFMA of the current tile.
// ---------------------------------------------------------------------------
template <typename TA, typename TC, int KDIM, int NCOLS, bool RELU, bool RESID>
__device__ __forceinline__ void gemm_core(const TA* __restrict__ A,
                                          const float* __restrict__ B,
                                          const float* __restrict__ bias,
                                          const float* __restrict__ resid,
                                          TC* __restrict__ C) {
    const int e   = blockIdx.z;
    const int rt  = blockIdx.x;            // row (token-slot) tile  [fast dim]
    const int ct  = blockIdx.y;            // col tile
    const int cnt = g_counts[e];
    if (rt * 64 >= cnt) return;            // uniform across block

    __shared__ __align__(16) __hip_bfloat16 sA[64 * 32];
    __shared__ __align__(16) __hip_bfloat16 sB[64 * 32];
    __shared__ int sTok[64];

    const int tid = threadIdx.x;

    if (tid < 64) {
        int slot = rt * 64 + tid;
        int cs   = slot < cnt ? slot : cnt - 1;   // clamp partial tile (dup row)
        sTok[tid] = g_idx[e * N_TOK + cs];
    }
    __syncthreads();

    // --- B staging (fp32): chunks c = {tid, tid+256}; row = c>>3, col = (c&7)*4
    const size_t bbase = ((size_t)e * NCOLS + (size_t)ct * 64) * KDIM;
    const int r2 = tid >> 3;               // 0..31
    const int c4 = (tid & 7) * 4;
    const float* gB0 = B + bbase + (size_t)r2 * KDIM + c4;
    const float* gB1 = B + bbase + (size_t)(r2 + 32) * KDIM + c4;

    // --- A staging ---
    const TA* gA0 = nullptr; const TA* gA1 = nullptr;   // fp32 path
    const TA* gAh = nullptr;                            // bf16 path
    int rowA = 0, ca = 0;
    if constexpr (std::is_same<TA, float>::value) {
        gA0 = A + (size_t)sTok[r2] * KDIM + c4;
        gA1 = A + (size_t)sTok[r2 + 32] * KDIM + c4;
    } else {
        rowA = tid >> 2;                   // 0..63
        ca   = (tid & 3) * 8;
        gAh  = A + (size_t)sTok[rowA] * KDIM + ca;
    }

    const int wave = tid >> 6;
    const int lane = tid & 63;
    const int wm = (wave >> 1) * 32;       // wave row offset in tile
    const int wn = (wave & 1) * 32;        // wave col offset in tile
    const int frow = lane & 15;
    const int fk   = (lane >> 4) * 8;

    f32x4 acc[2][2] = {};

    // prefetch registers
    f32x4 rb0, rb1, ra0, ra1;
    bf16x8 rah;

    auto load_tile = [&](int k0) {
        rb0 = *(const f32x4*)(gB0 + k0);
        rb1 = *(const f32x4*)(gB1 + k0);
        if constexpr (std::is_same<TA, float>::value) {
            ra0 = *(const f32x4*)(gA0 + k0);
            ra1 = *(const f32x4*)(gA1 + k0);
        } else {
            rah = *(const bf16x8*)(gAh + k0);
        }
    };
    auto store_tile = [&]() {
        *(bf16x4*)&sB[r2 * 32 + c4]        = cvt4(rb0);
        *(bf16x4*)&sB[(r2 + 32) * 32 + c4] = cvt4(rb1);
        if constexpr (std::is_same<TA, float>::value) {
            *(bf16x4*)&sA[r2 * 32 + c4]        = cvt4(ra0);
            *(bf16x4*)&sA[(r2 + 32) * 32 + c4] = cvt4(ra1);
        } else {
            *(bf16x8*)&sA[rowA * 32 + ca] = rah;
        }
    };

    load_tile(0);
    for (int k0 = 0; k0 < KDIM; k0 += 32) {
        __syncthreads();                   // prev LDS consumers done
        store_tile();                      // (waits vmcnt internally)
        __syncthreads();                   // staged data visible
        if (k0 + 32 < KDIM) load_tile(k0 + 32);   // issue next loads NOW

        bf16x8 af0, af1, bf0, bf1;
        const __hip_bfloat16* aptr = &sA[(wm + frow) * 32 + fk];
        const __hip_bfloat16* bptr = &sB[(wn + frow) * 32 + fk];
        af0 = *(const bf16x8*)(aptr);
        af1 = *(const bf16x8*)(aptr + 16 * 32);
        bf0 = *(const bf16x8*)(bptr);
        bf1 = *(const bf16x8*)(bptr + 16 * 32);
        acc[0][0] = __builtin_amdgcn_mfma_f32_16x16x32_bf16(af0, bf0, acc[0][0], 0, 0, 0);
        acc[0][1] = __builtin_amdgcn_mfma_f32_16x16x32_bf16(af0, bf1, acc[0][1], 0, 0, 0);
        acc[1][0] = __builtin_amdgcn_mfma_f32_16x16x32_bf16(af1, bf0, acc[1][0], 0, 0, 0);
        acc[1][1] = __builtin_amdgcn_mfma_f32_16x16x32_bf16(af1, bf1, acc[1][1], 0, 0, 0);
    }

    // epilogue: C/D layout col=lane&15, row=(lane>>4)*4+r  [m89/m91]
    const int crow = (lane >> 4) * 4;
    const int ccol = lane & 15;
#pragma unroll
    for (int j = 0; j < 2; ++j) {
        const int col = ct * 64 + wn + j * 16 + ccol;
        const float bv = bias[(size_t)e * NCOLS + col];
#pragma unroll
        for (int i = 0; i < 2; ++i) {
            const int rl = wm + i * 16 + crow;
#pragma unroll
            for (int r = 0; r < 4; ++r) {
                const int slot = rt * 64 + rl + r;
                if (slot < cnt) {
                    const int t = sTok[rl + r];
                    float v = acc[i][j][r] + bv;
                    if (RELU)  v = fmaxf(v, 0.0f);
                    if (RESID) v += resid[(size_t)t * NCOLS + col];
                    if constexpr (std::is_same<TC, float>::value)
                        C[(size_t)t * NCOLS + col] = v;
                    else
                        C[(size_t)t * NCOLS + col] = __float2bfloat16(v);
                }
            }
        }
    }
}

__global__ __launch_bounds__(256)
void gemm1_kernel(const float* __restrict__ x,
                  const float* __restrict__ W1,
                  const float* __restrict__ b1) {
    gemm_core<float, __hip_bfloat16, DDIM, MDIM, true, false>(x, W1, b1, nullptr, g_H);
}

__global__ __launch_bounds__(256)
void gemm2_kernel(const float* __restrict__ x,
                  const float* __restrict__ W2,
                  const float* __restrict__ b2,
                  float* __restrict__ out) {
    gemm_core<__hip_bfloat16, float, MDIM, DDIM, false, true>(
        (const __hip_bfloat16*)g_H, W2, b2, x, out);
}

extern "C" void kernel_launch(void* const* d_in, const int* in_sizes, int n_in,
                              void* d_out, int out_size, void* d_ws, size_t ws_size,
                              hipStream_t stream) {
    const float* x  = (const float*)d_in[0];
    const void*  dm = d_in[1];
    const float* W1 = (const float*)d_in[2];
    const float* b1 = (const float*)d_in[3];
    const float* W2 = (const float*)d_in[4];
    const float* b2 = (const float*)d_in[5];
    float* out = (float*)d_out;

    zero_counts_kernel<<<1, 64, 0, stream>>>();
    bucket_kernel<<<N_TOK / 256, 256, 0, stream>>>(dm);

    // GEMM1: H = relu(x @ W1[e]^T + b1[e])   [K=2048, cols=512]
    // rt = bx (128), ct = by (8): ct-neighbors are 128 apart -> same XCD.
    gemm1_kernel<<<dim3(N_TOK / 64, MDIM / 64, NEXP), 256, 0, stream>>>(x, W1, b1);

    // GEMM2: out = x + H @ W2[e]^T + b2[e]   [K=512, cols=2048]
    gemm2_kernel<<<dim3(N_TOK / 64, DDIM / 64, NEXP), 256, 0, stream>>>(x, W2, b2, out);
}